// Round 13
// baseline (40.056 us; speedup 1.0000x reference)
//
#include <hip/hip_runtime.h>

#define NPTS 16384
#define NBATCH 256
constexpr int THREADS  = 1024;           // 16 waves; one block per row/CU
constexpr int NW       = 16;
constexpr int NSTAGE   = 8;
constexpr int STAGEPTS = 2048;           // points per stage; 64 KB per stage
// j-order is stage-major: stage s covers [s*2048,(s+1)*2048); within a stage
// wave w owns 128 points, lane i owns 2 points at w*128 + i*2.
// DMA: wave w stages stream (w&7), half (w>>3) of each stage window.

__device__ __forceinline__ void dma16(const float* g, const float* l) {
  __builtin_amdgcn_global_load_lds(
      (const __attribute__((address_space(1))) void*)g,
      (__attribute__((address_space(3))) void*)l, 16, 0, 0);
}

__global__ __launch_bounds__(THREADS, 4) void row_loss_kernel(
    const float* __restrict__ o3, const float* __restrict__ s3,
    const float* __restrict__ o2, const float* __restrict__ s2,
    const float* __restrict__ df, float* __restrict__ out) {
  const int b = blockIdx.x;
  const int t = threadIdx.x;
  const int lane = t & 63;
  const int wave = t >> 6;

  __shared__ float lbuf[2][8][STAGEPTS];   // 128 KB double buffer
  __shared__ float wtot[3][NSTAGE][NW];    // per-stage per-wave totals
  __shared__ float redbuf[NW];

  // DMA source stream for this wave: sidx = wave&7, half h = wave>>3
  const int sidx = wave & 7;
  const int h = wave >> 3;
  const float* sp =
      (sidx < 3) ? (s3 + (size_t)b * 3 * NPTS + (size_t)sidx * NPTS)
    : (sidx < 6) ? (s2 + (size_t)b * 3 * NPTS + (size_t)(sidx - 3) * NPTS)
                 : (df + (size_t)b * 2 * NPTS + (size_t)(sidx - 6) * NPTS);

  // wave stages floats [s*2048 + h*1024, +1024) of its stream: 4 x 1KB DMA
  auto issue_stage = [&](int s, int bufi) {
    const float* src = sp + s * STAGEPTS + h * 1024 + lane * 4;
    const float* dst = &lbuf[bufi][sidx][h * 1024];   // wave-uniform base
    #pragma unroll
    for (int i = 0; i < 4; ++i) dma16(src + i * 256, dst + i * 256);
  };

  issue_stage(0, 0);
  __syncthreads();   // drain DMA(0)

  float px[NSTAGE][2], py[NSTAGE][2], pz[NSTAGE][2];  // wave-local prefixes

  #pragma unroll
  for (int s = 0; s < NSTAGE; ++s) {
    if (s + 1 < NSTAGE) issue_stage(s + 1, (s + 1) & 1);  // overlap with compute

    const int bi = s & 1;
    const int o = wave * 128 + lane * 2;
    const float2 R3 = *(const float2*)&lbuf[bi][0][o];
    const float2 T3 = *(const float2*)&lbuf[bi][1][o];
    const float2 P3 = *(const float2*)&lbuf[bi][2][o];
    const float2 R2 = *(const float2*)&lbuf[bi][3][o];
    const float2 T2 = *(const float2*)&lbuf[bi][4][o];
    const float2 P2 = *(const float2*)&lbuf[bi][5][o];
    const float2 DT = *(const float2*)&lbuf[bi][6][o];
    const float2 DP = *(const float2*)&lbuf[bi][7][o];

    float sx = 0.f, sy = 0.f, sz = 0.f;
    #pragma unroll
    for (int k = 0; k < 2; ++k) {
      float r3v = (&R3.x)[k];
      float th3 = (&T3.x)[k] + (&DT.x)[k];
      float ph3 = (&P3.x)[k] + (&DP.x)[k];
      float r2v = (&R2.x)[k];
      float th2 = (&T2.x)[k];
      float ph2 = (&P2.x)[k];
      float st3 = __sinf(th3), ct3 = __cosf(th3);
      float sp3 = __sinf(ph3), cp3 = __cosf(ph3);
      float st2 = __sinf(th2), ct2 = __cosf(th2);
      float sp2 = __sinf(ph2), cp2 = __cosf(ph2);
      sx += r3v * st3 * cp3 - r2v * st2 * cp2; px[s][k] = sx;
      sy += r3v * st3 * sp3 - r2v * st2 * sp2; py[s][k] = sy;
      sz += r3v * ct3 - r2v * ct2;             pz[s][k] = sz;
    }

    // lane scan of 2-pt totals; fold lane-exclusive offset into px
    float ix = sx, iy = sy, iz = sz;
    #pragma unroll
    for (int off = 1; off < 64; off <<= 1) {
      float ax = __shfl_up(ix, off, 64);
      float ay = __shfl_up(iy, off, 64);
      float az = __shfl_up(iz, off, 64);
      if (lane >= off) { ix += ax; iy += ay; iz += az; }
    }
    const float exx = ix - sx, exy = iy - sy, exz = iz - sz;
    px[s][0] += exx; px[s][1] += exx;
    py[s][0] += exy; py[s][1] += exy;
    pz[s][0] += exz; pz[s][1] += exz;
    if (lane == 63) { wtot[0][s][wave] = ix; wtot[1][s][wave] = iy; wtot[2][s][wave] = iz; }

    __syncthreads();  // drains DMA(s+1); buffer bi consumed by all waves
  }

  // ---- per-(stage,wave) offsets from wtot (uniform LDS broadcasts) ----
  float offx[NSTAGE], offy[NSTAGE], offz[NSTAGE];
  float cx = 0.f, cy = 0.f, cz = 0.f;
  #pragma unroll
  for (int s = 0; s < NSTAGE; ++s) {
    float wpx = 0.f, wpy = 0.f, wpz = 0.f, tx = 0.f, ty = 0.f, tz = 0.f;
    #pragma unroll
    for (int w = 0; w < NW; ++w) {
      float vx = wtot[0][s][w], vy = wtot[1][s][w], vz = wtot[2][s][w];
      if (w < wave) { wpx += vx; wpy += vy; wpz += vz; }
      tx += vx; ty += vy; tz += vz;
    }
    offx[s] = cx + wpx; offy[s] = cy + wpy; offz[s] = cz + wpz;
    cx += tx; cy += ty; cz += tz;
  }

  // row carry = origin diff
  const float ox = o3[b * 3 + 0] - o2[b * 3 + 0];
  const float oy = o3[b * 3 + 1] - o2[b * 3 + 1];
  const float oz = o3[b * 3 + 2] - o2[b * 3 + 2];

  // ---- abs over in-register prefixes ----
  float acc = 0.f;
  #pragma unroll
  for (int s = 0; s < NSTAGE; ++s) {
    const float gx = ox + offx[s], gy = oy + offy[s], gz = oz + offz[s];
    acc += fabsf(gx + px[s][0]) + fabsf(gx + px[s][1]);
    acc += fabsf(gy + py[s][0]) + fabsf(gy + py[s][1]);
    acc += fabsf(gz + pz[s][0]) + fabsf(gz + pz[s][1]);
  }
  if (t == 0) acc += fabsf(ox) + fabsf(oy) + fabsf(oz);  // j=0 cumsum term

  // ---- block reduction + one atomic per row ----
  #pragma unroll
  for (int off = 32; off > 0; off >>= 1) acc += __shfl_down(acc, off, 64);
  if (lane == 0) redbuf[wave] = acc;
  __syncthreads();
  if (t == 0) {
    float s = 0.f;
    #pragma unroll
    for (int w = 0; w < NW; ++w) s += redbuf[w];
    atomicAdd(out, s * (1.0f / (float)(NPTS + 1)));
  }
}

extern "C" void kernel_launch(void* const* d_in, const int* in_sizes, int n_in,
                              void* d_out, int out_size, void* d_ws, size_t ws_size,
                              hipStream_t stream) {
  const float* o3 = (const float*)d_in[0];  // origin_3D      (B,3,1)
  const float* s3 = (const float*)d_in[1];  // spherical_3D   (B,3,N)
  const float* o2 = (const float*)d_in[2];  // origin_2D      (B,3,1)
  const float* s2 = (const float*)d_in[3];  // spherical_2D   (B,3,N)
  const float* df = (const float*)d_in[4];  // deformation    (B,2,N)
  float* out = (float*)d_out;

  // out accumulates via atomicAdd; harness doesn't re-zero between replays.
  hipMemsetAsync(out, 0, sizeof(float) * out_size, stream);
  row_loss_kernel<<<NBATCH, THREADS, 0, stream>>>(o3, s3, o2, s2, df, out);
}

// Round 14
// 33.510 us; speedup vs baseline: 1.1953x; 1.1953x over previous
//
#include <hip/hip_runtime.h>

#define NPTS 16384
#define NBATCH 256
constexpr int THREADS = 1024;            // 16 waves; one block per row/CU
constexpr int NW      = THREADS / 64;    // 16 waves
// wave w owns points [w*1024,(w+1)*1024); lane i owns 4-pt mini-windows at
// w*1024 + gg*256 + i*4. Load order of the 4 windows is ROTATED per wave
// (gg = (g + wave + block) & 3) to spread instantaneous addresses across the
// HBM channel-interleave period (anti channel-camping). The scan is restored
// to j-order via an LDS table of per-(wave,window) totals.

__device__ __forceinline__ float4 ld4(const float* p) {
  return *reinterpret_cast<const float4*>(p);
}

__global__ __launch_bounds__(THREADS, 4) void row_loss_kernel(
    const float* __restrict__ o3, const float* __restrict__ s3,
    const float* __restrict__ o2, const float* __restrict__ s2,
    const float* __restrict__ df, float* __restrict__ out) {
  const int b = blockIdx.x;
  const int t = threadIdx.x;
  const int lane = t & 63;
  const int wave = t >> 6;

  __shared__ float wtot[3][NW][4];   // per-(wave, j-window) totals
  __shared__ float redbuf[NW];

  const float* r3p = s3 + (size_t)b * 3 * NPTS;
  const float* t3p = r3p + NPTS;
  const float* p3p = r3p + 2 * NPTS;
  const float* r2p = s2 + (size_t)b * 3 * NPTS;
  const float* t2p = r2p + NPTS;
  const float* p2p = r2p + 2 * NPTS;
  const float* dtp = df + (size_t)b * 2 * NPTS;
  const float* dpp = dtp + NPTS;

  const int wbase = wave * 1024;
  const int rot = (wave + b) & 3;

  // ---- Phase 1: rotated-window loads, trig, per-window lane-prefix ----
  // px[g][k] ends as: (exclusive lane offset within window) + (point prefix)
  float px[4][4], py[4][4], pz[4][4];
  #pragma unroll
  for (int g = 0; g < 4; ++g) {
    const int gg = (g + rot) & 3;                 // j-window this g handles
    const int idx = wbase + gg * 256 + lane * 4;
    float4 R3 = ld4(r3p + idx), T3 = ld4(t3p + idx);
    float4 P3 = ld4(p3p + idx), R2 = ld4(r2p + idx);
    float4 T2 = ld4(t2p + idx), P2 = ld4(p2p + idx);
    float4 DT = ld4(dtp + idx), DP = ld4(dpp + idx);
    float sx = 0.f, sy = 0.f, sz = 0.f;
    #pragma unroll
    for (int k = 0; k < 4; ++k) {
      float r3v = ((const float*)&R3)[k];
      float th3 = ((const float*)&T3)[k] + ((const float*)&DT)[k];
      float ph3 = ((const float*)&P3)[k] + ((const float*)&DP)[k];
      float r2v = ((const float*)&R2)[k];
      float th2 = ((const float*)&T2)[k];
      float ph2 = ((const float*)&P2)[k];
      float st3 = __sinf(th3), ct3 = __cosf(th3);
      float sp3 = __sinf(ph3), cp3 = __cosf(ph3);
      float st2 = __sinf(th2), ct2 = __cosf(th2);
      float sp2 = __sinf(ph2), cp2 = __cosf(ph2);
      sx += r3v * st3 * cp3 - r2v * st2 * cp2; px[g][k] = sx;
      sy += r3v * st3 * sp3 - r2v * st2 * sp2; py[g][k] = sy;
      sz += r3v * ct3 - r2v * ct2;             pz[g][k] = sz;
    }
    // lane scan of window totals -> exclusive lane offset folded into px
    float ix = sx, iy = sy, iz = sz;
    #pragma unroll
    for (int off = 1; off < 64; off <<= 1) {
      float ax = __shfl_up(ix, off, 64);
      float ay = __shfl_up(iy, off, 64);
      float az = __shfl_up(iz, off, 64);
      if (lane >= off) { ix += ax; iy += ay; iz += az; }
    }
    const float exx = ix - sx, exy = iy - sy, exz = iz - sz;
    #pragma unroll
    for (int k = 0; k < 4; ++k) { px[g][k] += exx; py[g][k] += exy; pz[g][k] += exz; }
    if (lane == 63) {               // window total at its j-position
      wtot[0][wave][gg] = ix; wtot[1][wave][gg] = iy; wtot[2][wave][gg] = iz;
    }
  }
  __syncthreads();

  // ---- Phase 2: j-order offsets from the LDS table ----
  // base = sum over all windows of waves before this wave (wave-uniform branch)
  float basex = 0.f, basey = 0.f, basez = 0.f;
  #pragma unroll
  for (int w = 0; w < NW; ++w) {
    if (w < wave) {
      #pragma unroll
      for (int h = 0; h < 4; ++h) {
        basex += wtot[0][w][h]; basey += wtot[1][w][h]; basez += wtot[2][w][h];
      }
    }
  }
  // prefix over this wave's earlier windows (static arrays, selected per g)
  float phx[4], phy[4], phz[4];
  phx[0] = 0.f; phy[0] = 0.f; phz[0] = 0.f;
  #pragma unroll
  for (int h = 1; h < 4; ++h) {
    phx[h] = phx[h-1] + wtot[0][wave][h-1];
    phy[h] = phy[h-1] + wtot[1][wave][h-1];
    phz[h] = phz[h-1] + wtot[2][wave][h-1];
  }

  // row carry = origin diff (uniform scalar loads)
  const float ox = o3[b * 3 + 0] - o2[b * 3 + 0];
  const float oy = o3[b * 3 + 1] - o2[b * 3 + 1];
  const float oz = o3[b * 3 + 2] - o2[b * 3 + 2];
  const float Bx = ox + basex, By = oy + basey, Bz = oz + basez;

  // ---- Phase 3: abs over in-register prefixes ----
  float acc = 0.f;
  #pragma unroll
  for (int g = 0; g < 4; ++g) {
    const int gg = (g + rot) & 3;
    const float sx = (gg == 0) ? phx[0] : (gg == 1) ? phx[1] : (gg == 2) ? phx[2] : phx[3];
    const float sy = (gg == 0) ? phy[0] : (gg == 1) ? phy[1] : (gg == 2) ? phy[2] : phy[3];
    const float sz = (gg == 0) ? phz[0] : (gg == 1) ? phz[1] : (gg == 2) ? phz[2] : phz[3];
    const float gx = Bx + sx, gy = By + sy, gz = Bz + sz;
    #pragma unroll
    for (int k = 0; k < 4; ++k) {
      acc += fabsf(gx + px[g][k]) + fabsf(gy + py[g][k]) + fabsf(gz + pz[g][k]);
    }
  }
  if (t == 0) acc += fabsf(ox) + fabsf(oy) + fabsf(oz);  // j=0 cumsum term

  // ---- block reduction + one atomic per row ----
  #pragma unroll
  for (int off = 32; off > 0; off >>= 1) acc += __shfl_down(acc, off, 64);
  if (lane == 0) redbuf[wave] = acc;
  __syncthreads();
  if (t == 0) {
    float s = 0.f;
    #pragma unroll
    for (int w = 0; w < NW; ++w) s += redbuf[w];
    atomicAdd(out, s * (1.0f / (float)(NPTS + 1)));
  }
}

extern "C" void kernel_launch(void* const* d_in, const int* in_sizes, int n_in,
                              void* d_out, int out_size, void* d_ws, size_t ws_size,
                              hipStream_t stream) {
  const float* o3 = (const float*)d_in[0];  // origin_3D      (B,3,1)
  const float* s3 = (const float*)d_in[1];  // spherical_3D   (B,3,N)
  const float* o2 = (const float*)d_in[2];  // origin_2D      (B,3,1)
  const float* s2 = (const float*)d_in[3];  // spherical_2D   (B,3,N)
  const float* df = (const float*)d_in[4];  // deformation    (B,2,N)
  float* out = (float*)d_out;

  // out accumulates via atomicAdd; harness doesn't re-zero between replays.
  hipMemsetAsync(out, 0, sizeof(float) * out_size, stream);
  row_loss_kernel<<<NBATCH, THREADS, 0, stream>>>(o3, s3, o2, s2, df, out);
}